// Round 9
// baseline (178.729 us; speedup 1.0000x reference)
//
#include <hip/hip_runtime.h>
#include <stdint.h>

#define M_PIX 8192
#define N_CB  16384
#define KD    256

typedef float f32x4 __attribute__((ext_vector_type(4)));
typedef long long ll2 __attribute__((ext_vector_type(2)));
typedef unsigned long long ull;

// workspace layout (bytes)
#define OFF_CF8  (0ULL)            // codebook fp8 e4m3 (permuted rows) : 4 MB
#define OFF_XF8  (4ULL << 20)      // x fp8 e4m3 (permuted rows)        : 2 MB
#define OFF_CBSQ (6ULL << 20)      // ||c||^2 fp32                      : 64 KB
#define OFF_SLOT (7ULL << 20)      // float2 top2 [tile][pixel]         : 8 MB
#define WS_REQ   (15ULL << 20)

__device__ __forceinline__ unsigned int fkey(float s) {
  unsigned int f = __float_as_uint(s);
  return f ^ ((unsigned int)(((int)f) >> 31) | 0x80000000u);
}
// fp32 -> OCP e4m3fn, RNE, handles subnormals (step 2^-9), clamp 448
__device__ __forceinline__ unsigned char f2e4m3(float v) {
  float av = fminf(fabsf(v), 448.0f);
  const unsigned s = (__float_as_uint(v) >> 24) & 0x80u;
  unsigned m;
  if (av >= 0.015625f) {              // normal: round at mantissa bit 20
    unsigned u = __float_as_uint(av);
    u += 0x7FFFFu + ((u >> 20) & 1u);
    m = (((u >> 23) - 120u) << 3) | ((u >> 20) & 7u);
  } else {                            // subnormal
    m = (unsigned)(int)rintf(av * 512.0f);
  }
  return (unsigned char)(s | m);
}
__device__ __forceinline__ void gl_lds16(const unsigned char* g, char* l) {
  __builtin_amdgcn_global_load_lds(
      (const __attribute__((address_space(1))) unsigned int*)(const void*)g,
      (__attribute__((address_space(3))) unsigned int*)(void*)l,
      16, 0, 0);
}
// keep-smallest-2 on packed float keys: 3 VALU, no cndmask
__device__ __forceinline__ void ins2f(float k, float& v1, float& v2) {
  v2 = fminf(v2, fmaxf(v1, k));   // uses OLD v1
  v1 = fminf(v1, k);
}

// ---------------- kernel 1: fp32 -> fp8 e4m3 permuted rows + cb norms -------
// Row permutation: element k (b7=half, b6-5=kb, b4-3=q, b2-0=j) stored at
// byte p = half<<7 | q<<5 | kb<<3 | j. One 16B granule = frags for two
// consecutive k-blocks of one q-group.
__global__ __launch_bounds__(256) void prep_kernel(
    const float* __restrict__ x, const float* __restrict__ cb,
    unsigned char* __restrict__ Cf8, unsigned char* __restrict__ Xf8,
    float* __restrict__ cbsq) {
  const int wid = threadIdx.x >> 6, lane = threadIdx.x & 63;
  const int row = blockIdx.x * 4 + wid;        // grid = (N_CB+M_PIX)/4
  const bool isCb = (row < N_CB);
  const int rowL = isCb ? row : row - N_CB;
  const float* src = (isCb ? cb : x) + (size_t)rowL * KD;
  const float4 v = ((const float4*)src)[lane];
  const int k0 = lane * 4;
  const int p0 = (k0 & 0x87) | ((k0 & 0x18) << 2) | ((k0 >> 2) & 0x18);
  uchar4 pk;
  pk.x = f2e4m3(v.x); pk.y = f2e4m3(v.y); pk.z = f2e4m3(v.z); pk.w = f2e4m3(v.w);
  *(uchar4*)(void*)((isCb ? Cf8 : Xf8) + (size_t)rowL * KD + p0) = pk;
  if (isCb) {
    float ss = v.x*v.x + v.y*v.y + v.z*v.z + v.w*v.w;   // fp32 norm
    #pragma unroll
    for (int off = 32; off > 0; off >>= 1) ss += __shfl_xor(ss, off);
    if (lane == 0) cbsq[rowL] = ss;
  }
}

// ---------------- kernel 2: fp8 GEMM + per-tile top-2 -----------------------
// s[p,n] = cbsq[n] - 2*(x8.c8). 8192 blocks / 4 waves (2x2, wave tile 64x64).
// K staged in two 128-col halves; A,B = 16 KB each, row stride 128 B.
// XOR granule swizzle: LDS(row, gp) holds logical granule gp ^ (row&7) ->
// within any ds_read_b128 the 64 lanes spread 8-per-4-bank-group (minimum
// schedule, 0 conflicts; round-5 signature). Frag addr = base ^ (kp<<4).
// Epilogue planes [128][36] fp32 overlay the dead tiles.

__global__ __launch_bounds__(256, 4) void gemm_top2_kernel(
    const unsigned char* __restrict__ Xf8, const unsigned char* __restrict__ Cf8,
    const float* __restrict__ cbsq, float2* __restrict__ slots) {
  __shared__ __align__(16) char smem[36864];
  char* A_s = smem;                       // 16 KB [128][128B]
  char* B_s = smem + 16384;               // 16 KB
  float* v1p = (float*)smem;              // overlay: [128][36] = 18432 B
  float* v2p = (float*)(smem + 18432);    // overlay: [128][36]

  const int tid = threadIdx.x;
  const int wid = tid >> 6, lane = tid & 63;
  const int wy = wid >> 1, wx = wid & 1;
  const int q = lane >> 4, c = lane & 15;

  // m-outer / n-inner per XCD: 16-block sweeps share one A-tile + B-strip
  const int bx = blockIdx.x & 7, bg = blockIdx.x >> 3;
  const int mt = bg >> 4;               // 0..63
  const int nt = bx * 16 + (bg & 15);   // 0..127
  const int m0 = mt * 128, n0 = nt * 128;

  // per-lane LDS frag byte bases with swizzle: row*128 + ((2q ^ (c&7)) << 4)
  int abase[4], bbase[4];
  #pragma unroll
  for (int i = 0; i < 4; i++) {
    abase[i] = (wy * 64 + i * 16 + c) * 128 + (((2 * q) ^ (c & 7)) << 4);
    bbase[i] = (wx * 64 + i * 16 + c) * 128 + (((2 * q) ^ (c & 7)) << 4);
  }

  const f32x4 zf = {0.f, 0.f, 0.f, 0.f};
  f32x4 acc[4][4];
  #pragma unroll
  for (int i = 0; i < 4; i++)
    #pragma unroll
    for (int j = 0; j < 4; j++) acc[i][j] = zf;

  // staging source granule: dest gp = lane&7, row&7 = (lane>>3)&7
  const int sg = (lane & 7) ^ ((lane >> 3) & 7);

  #pragma unroll
  for (int hk = 0; hk < 2; hk++) {        // two 128-col K-halves
    if (hk) __syncthreads();              // prior half's frag reads done
    #pragma unroll
    for (int j = 0; j < 4; j++) {         // 16 chunks of 1 KB per operand
      const int chunk = j * 4 + wid;      // wave-uniform
      const int row = chunk * 8 + (lane >> 3);
      const int gb = sg * 16 + hk * 128;
      gl_lds16(Xf8 + (size_t)(m0 + row) * KD + gb, A_s + chunk * 1024);
      gl_lds16(Cf8 + (size_t)(n0 + row) * KD + gb, B_s + chunk * 1024);
    }
    __syncthreads();
    #pragma unroll
    for (int kp = 0; kp < 2; kp++) {      // kb-pairs; addr = base ^ (kp<<4)
      ll2 bfr[4];
      #pragma unroll
      for (int ni = 0; ni < 4; ni++)
        bfr[ni] = *(const ll2*)(const void*)(B_s + (bbase[ni] ^ (kp << 4)));
      #pragma unroll
      for (int mi = 0; mi < 4; mi++) {
        const ll2 af = *(const ll2*)(const void*)(A_s + (abase[mi] ^ (kp << 4)));
        #pragma unroll
        for (int ni = 0; ni < 4; ni++) {
          acc[mi][ni] = __builtin_amdgcn_mfma_f32_16x16x32_fp8_fp8(af.x, bfr[ni].x, acc[mi][ni], 0, 0, 0);
          acc[mi][ni] = __builtin_amdgcn_mfma_f32_16x16x32_fp8_fp8(af.y, bfr[ni].y, acc[mi][ni], 0, 0, 0);
        }
      }
    }
  }
  __syncthreads();   // tiles dead -> overlay planes

  float cs[4]; unsigned colp[4];
  #pragma unroll
  for (int ni = 0; ni < 4; ni++) {
    colp[ni] = wx * 64 + ni * 16 + c;
    cs[ni] = cbsq[n0 + colp[ni]];
  }
  const float FINF = __uint_as_float(0x7F800000u);

  // owner phase: C/D layout col=lane&15, row=q*4+reg (m89/m91); col packed
  // into low 7 mantissa bits (|err|<=0.008, absorbed by k3 threshold)
  #pragma unroll
  for (int mi = 0; mi < 4; mi++) {
    #pragma unroll
    for (int r = 0; r < 4; r++) {
      float v1 = FINF, v2 = FINF;
      #pragma unroll
      for (int ni = 0; ni < 4; ni++) {
        const float s = fmaf(-2.f, acc[mi][ni][r], cs[ni]);
        ins2f(__uint_as_float((__float_as_uint(s) & 0xFFFFFF80u) | colp[ni]),
              v1, v2);
      }
      const int row = wy * 64 + mi * 16 + q * 4 + r;
      const int slot = wx * 16 + c;
      v1p[row * 36 + slot] = v1;
      v2p[row * 36 + slot] = v2;
    }
  }
  __syncthreads();

  // scan: 2 threads/row over 16 partial-pairs each, 1 shuffle merge
  {
    const int srow = tid >> 1, half = tid & 1;
    float v1 = FINF, v2 = FINF;
    #pragma unroll
    for (int jj = 0; jj < 2; jj++) {
      const float4 a  = *(const float4*)(const void*)(v1p + srow * 36 + half * 16 + jj * 8);
      const float4 a2 = *(const float4*)(const void*)(v1p + srow * 36 + half * 16 + jj * 8 + 4);
      const float4 b  = *(const float4*)(const void*)(v2p + srow * 36 + half * 16 + jj * 8);
      const float4 b2 = *(const float4*)(const void*)(v2p + srow * 36 + half * 16 + jj * 8 + 4);
      ins2f(a.x, v1, v2);  ins2f(a.y, v1, v2);
      ins2f(a.z, v1, v2);  ins2f(a.w, v1, v2);
      ins2f(a2.x, v1, v2); ins2f(a2.y, v1, v2);
      ins2f(a2.z, v1, v2); ins2f(a2.w, v1, v2);
      ins2f(b.x, v1, v2);  ins2f(b.y, v1, v2);
      ins2f(b.z, v1, v2);  ins2f(b.w, v1, v2);
      ins2f(b2.x, v1, v2); ins2f(b2.y, v1, v2);
      ins2f(b2.z, v1, v2); ins2f(b2.w, v1, v2);
    }
    const float b1 = __shfl_xor(v1, 1), b2 = __shfl_xor(v2, 1);
    const float hi = fmaxf(v1, b1);
    v1 = fminf(v1, b1);
    v2 = fminf(fminf(v2, b2), hi);
    if (!half)
      slots[(size_t)nt * M_PIX + m0 + srow] = make_float2(v1, v2);
  }
}

// ---------------- kernel 3: block-per-64-pixels, coalesced ------------------
// Phase 1: per-pixel min over all 128 tiles (coalesced 512B sweeps).
// Phase 2: candidates with observed < min+10 -> LDS list (tile from sweep,
// col from low 7 mantissa bits). Phase 3: exact fp32 rescore per candidate
// (one wave each, single-writer LDS best slots). Phase 4: coalesced gather.
__global__ __launch_bounds__(256) void reduce_rescore_gather(
    const float* __restrict__ x, const float* __restrict__ cb,
    const float* __restrict__ cbsq, const float2* __restrict__ slots,
    float* __restrict__ out) {
  __shared__ float pmin[64][4];
  __shared__ ull wbest[64][4];
  __shared__ unsigned cand[1536];
  __shared__ int ncand;

  const int tid = threadIdx.x;
  const int wid = tid >> 6, lane = tid & 63;
  const int P0 = blockIdx.x * 64;       // grid = 128 blocks
  const int pl = tid & 63;              // this thread's pixel (phases 1-2)
  const int tg = tid >> 6;              // tile-group 0..3

  if (tid < 64) {
    #pragma unroll
    for (int w = 0; w < 4; w++) wbest[tid][w] = ~0ULL;
  }
  if (tid == 0) ncand = 0;

  const float FINF = __uint_as_float(0x7F800000u);
  float m = FINF;
  for (int s = 0; s < 32; s++) {        // tiles tg, tg+4, ..., coalesced 512B
    const float2 v = slots[(size_t)(s * 4 + tg) * M_PIX + P0 + pl];
    m = fminf(m, v.x);
  }
  pmin[pl][tg] = m;
  __syncthreads();
  const float thr = fminf(fminf(pmin[pl][0], pmin[pl][1]),
                          fminf(pmin[pl][2], pmin[pl][3])) + 10.0f;

  for (int s = 0; s < 32; s++) {        // re-sweep (L1/L2-hot), collect cands
    const int t = s * 4 + tg;
    const float2 v = slots[(size_t)t * M_PIX + P0 + pl];
    if (v.x < thr) {
      const int i = atomicAdd(&ncand, 1);
      if (i < 1536)
        cand[i] = ((unsigned)pl << 14) | (unsigned)(t * 128 + (__float_as_uint(v.x) & 127u));
    }
    if (v.y < thr) {
      const int i = atomicAdd(&ncand, 1);
      if (i < 1536)
        cand[i] = ((unsigned)pl << 14) | (unsigned)(t * 128 + (__float_as_uint(v.y) & 127u));
    }
  }
  __syncthreads();

  const int nc = min(ncand, 1536);
  for (int ci = wid; ci < nc; ci += 4) {   // one candidate per wave
    const unsigned e = cand[ci];
    const int p = (int)(e >> 14);
    const unsigned ij = e & 0x3FFFu;
    const float4 xv = ((const float4*)x)[(size_t)(P0 + p) * 64 + lane];
    const float4 cv = ((const float4*)cb)[(size_t)ij * 64 + lane];
    float d = xv.x*cv.x + xv.y*cv.y + xv.z*cv.z + xv.w*cv.w;
    #pragma unroll
    for (int off = 1; off < 64; off <<= 1) d += __shfl_xor(d, off);
    if (lane == 0) {
      const float sv = fmaf(-2.f, d, cbsq[ij]);
      const ull k = ((ull)fkey(sv) << 32) | ij;   // tie -> lowest idx (np)
      const ull cur = wbest[p][wid];              // single writer, sequential
      wbest[p][wid] = k < cur ? k : cur;
    }
  }
  __syncthreads();

  #pragma unroll
  for (int r = 0; r < 16; r++) {        // coalesced out writes, 64 KB/block
    const int p = r * 4 + wid;
    const ull b0 = wbest[p][0], b1 = wbest[p][1],
              b2 = wbest[p][2], b3 = wbest[p][3];
    ull b = b0 < b1 ? b0 : b1;
    const ull b23 = b2 < b3 ? b2 : b3;
    b = b < b23 ? b : b23;
    const unsigned w = (unsigned)b;
    ((float4*)out)[(size_t)(P0 + p) * 64 + lane] = ((const float4*)cb)[(size_t)w * 64 + lane];
  }
}

// ---------------- fallback (ws too small): exact fp32 scan ------------------
__global__ __launch_bounds__(256) void fallback_kernel(
    const float* __restrict__ x, const float* __restrict__ cb,
    float* __restrict__ out) {
  __shared__ float xs[256];
  __shared__ unsigned long long keys[4];
  __shared__ int widx;
  const int p = blockIdx.x;
  const int tid = threadIdx.x, wid = tid >> 6, lane = tid & 63;
  xs[tid] = x[(size_t)p * KD + tid];
  __syncthreads();
  const float4 xv = ((const float4*)xs)[lane];
  float bestS = 3.4e38f; int bestI = 0;
  for (int k = wid; k < N_CB; k += 4) {
    const float4 cv = ((const float4*)cb)[(size_t)k * 64 + lane];
    float t = cv.x*(cv.x - 2.f*xv.x) + cv.y*(cv.y - 2.f*xv.y)
            + cv.z*(cv.z - 2.f*xv.z) + cv.w*(cv.w - 2.f*xv.w);
    #pragma unroll
    for (int off = 1; off < 64; off <<= 1) t += __shfl_xor(t, off);
    if (t < bestS) { bestS = t; bestI = k; }
  }
  if (lane == 0)
    keys[wid] = ((unsigned long long)fkey(bestS) << 32) | (unsigned int)bestI;
  __syncthreads();
  if (tid == 0) {
    unsigned long long m = keys[0];
    for (int i = 1; i < 4; i++) if (keys[i] < m) m = keys[i];
    widx = (int)(unsigned int)(m & 0xFFFFFFFFULL);
  }
  __syncthreads();
  out[(size_t)p * KD + tid] = cb[(size_t)widx * KD + tid];
}

extern "C" void kernel_launch(void* const* d_in, const int* in_sizes, int n_in,
                              void* d_out, int out_size, void* d_ws, size_t ws_size,
                              hipStream_t stream) {
  const float* x  = (const float*)d_in[0];   // [8192,256]
  const float* cb = (const float*)d_in[1];   // [16384,256]
  float* out = (float*)d_out;                // [8192,256]

  if (ws_size < WS_REQ) {
    fallback_kernel<<<M_PIX, 256, 0, stream>>>(x, cb, out);
    return;
  }

  char* ws = (char*)d_ws;
  unsigned char* Cf8 = (unsigned char*)(ws + OFF_CF8);
  unsigned char* Xf8 = (unsigned char*)(ws + OFF_XF8);
  float* cbsq        = (float*)(ws + OFF_CBSQ);
  float2* slots      = (float2*)(ws + OFF_SLOT);

  prep_kernel<<<(N_CB + M_PIX) / 4, 256, 0, stream>>>(x, cb, Cf8, Xf8, cbsq);
  gemm_top2_kernel<<<M_PIX, 256, 0, stream>>>(Xf8, Cf8, cbsq, slots);
  reduce_rescore_gather<<<M_PIX / 64, 256, 0, stream>>>(x, cb, cbsq, slots, out);
}